// Round 6
// baseline (401.285 us; speedup 1.0000x reference)
//
#include <hip/hip_runtime.h>

// MoonVitEncoderLayer on MI355X (gfx950).
// S=4096, D=1152, H=16, HD=72 (padded to 96), MLPD=4304 (padded to 4352).
// cu_seqlens is always arange(9)*512 -> block-diagonal attention, 8 segs of 512.
// R5: m201-style 256x256x64 8-phase GEMM (T2+T3+T4+T5), 8 waves 2Mx4N,
//     per-wave 128x64 acc[8][4], 128KB LDS dbuf, one 16KB stage-unit per phase,
//     vmcnt(6) checkpoints at phases 3/7. qkv N->3584, wo/fc1 N->1280 pads;
//     fc1 split-K2 + f32 reduce. rope_pack vectorized short8.

#define DEV __device__ __forceinline__

typedef __attribute__((ext_vector_type(8))) short short8;
typedef __attribute__((ext_vector_type(4))) float f32x4;

typedef const void __attribute__((address_space(1))) gvoid;
typedef void __attribute__((address_space(3))) lvoid;

DEV ushort f2bf(float f) {
  union { float f; unsigned u; } x; x.f = f;
  unsigned r = (x.u + 0x7FFFu + ((x.u >> 16) & 1u)) >> 16;
  return (ushort)r;
}

DEV float bf2f(ushort u) {
  union { unsigned u; float f; } x; x.u = (unsigned)u << 16;
  return x.f;
}

DEV void gload_lds16(const void* g, void* l) {
  __builtin_amdgcn_global_load_lds((gvoid*)g, (lvoid*)l, 16, 0, 0);
}

DEV f32x4 mfma16(short8 a, short8 b, f32x4 c) {
  return __builtin_amdgcn_mfma_f32_16x16x32_bf16(a, b, c, 0, 0, 0);
}

DEV float gelu_tanh(float x) {
  float x3 = x * x * x;
  return 0.5f * x * (1.f + tanhf(0.7978845608f * (x + 0.044715f * x3)));
}

// ---------------- weight convert + transpose: src f32 (K,N) -> dst bf16 (NP,KP), zero-padded
__global__ void wconv_t(const float* __restrict__ src, ushort* __restrict__ dst,
                        int K, int N, int NP, int KP) {
  __shared__ float tile[32][33];
  const int k0 = blockIdx.x * 32, n0 = blockIdx.y * 32;
  const int tx = threadIdx.x & 31, ty = threadIdx.x >> 5; // ty 0..7
#pragma unroll
  for (int i = 0; i < 4; ++i) {
    int r = ty + i * 8;
    float v = 0.f;
    if (k0 + r < K && n0 + tx < N) v = src[(size_t)(k0 + r) * N + n0 + tx];
    tile[tx][r] = v;
  }
  __syncthreads();
#pragma unroll
  for (int i = 0; i < 4; ++i) {
    int r = ty + i * 8;
    dst[(size_t)(n0 + r) * KP + k0 + tx] = f2bf(tile[r][tx]);
  }
}

// ---------------- LayerNorm row kernel: f32 (4096,1152) -> bf16
__global__ __launch_bounds__(256) void ln_bf16(const float* __restrict__ x,
                                               const float* __restrict__ sc,
                                               const float* __restrict__ bi,
                                               ushort* __restrict__ out) {
  const int row = blockIdx.x, tid = threadIdx.x;
  const float* xr = x + (size_t)row * 1152;
  const int n = (tid < 128) ? 5 : 4;
  float vals[5];
  float s = 0.f, s2 = 0.f;
#pragma unroll
  for (int i = 0; i < 5; ++i) {
    if (i < n) { float v = xr[tid + i * 256]; vals[i] = v; s += v; s2 += v * v; }
  }
#pragma unroll
  for (int off = 32; off; off >>= 1) { s += __shfl_xor(s, off); s2 += __shfl_xor(s2, off); }
  __shared__ float rs[4], rs2[4];
  if ((tid & 63) == 0) { rs[tid >> 6] = s; rs2[tid >> 6] = s2; }
  __syncthreads();
  s = rs[0] + rs[1] + rs[2] + rs[3];
  s2 = rs2[0] + rs2[1] + rs2[2] + rs2[3];
  const float mean = s * (1.f / 1152.f);
  const float var = s2 * (1.f / 1152.f) - mean * mean;
  const float rstd = rsqrtf(var + 1e-5f);
  ushort* orow = out + (size_t)row * 1152;
  for (int i = 0; i < n; ++i) {
    int c = tid + i * 256;
    orow[c] = f2bf((vals[i] - mean) * rstd * sc[c] + bi[c]);
  }
}

// ---------------- 8-phase 256x256x64 GEMM (m201 template, plain HIP)
// A (M,K) bf16 rm, Bt (NP,K) bf16 rm (N-rows, zero-padded), C = A*B.
// 512 thr = 8 waves (wr=wave>>2 in {0,1}, wc=wave&3); per-wave C = 128x64.
// Tile T (BK=64) split into register stages: aL (mf0-3), aH (mf4-7),
// b01 (nf0-1), b23 (nf2-3). Quadrants: Q1=aLxb01, Q2=aLxb23, Q3=aHxb01,
// Q4=aHxb23 (16 MFMA each). Reads for quadrant q+1 issued during phase q.
// LDS: 2 bufs x (A 32KB + B 32KB) = 128KB; tile parity -> buffer.
// Stage units (16KB, 2 gloads/thread): A-low {rows 0-63,128-191},
// A-up {64-127,192-255}, B-first {n 0-31,64-95,128-159,192-223}, B-second (+32).
// Per-phase stage schedule (iter = tiles T0 buf0 / T1 buf1, stage T2/T3):
//  ph1:T2.Alow ph2:T2.Bfst ph3:T2.Aup ph4:T2.Bsnd ph5:T3.Alow ph6:T3.Bfst
//  ph7:T3.Aup ph8:T3.Bsnd  -- each unit staged only after its region's last
// reader retired (aH read ph2 -> staged ph3, etc.); vmcnt(6) before barB of
// ph3/ph7 certifies all but the newest 3 units before their first readers.
// XOR swizzle (R4-verified, 0 conflicts): global k-chunk pre-swizzled by
// (tid&7)^(row&7); read chunk cph = (ks*4+lg)^(l15&7).
// EPI 0: split-K partial (no bias)  1: resid+C+bias  2: bf16(gelu(C+bias))
// EPI 3: bf16(C+bias)
#define BAR __builtin_amdgcn_s_barrier()
#define LGKM0 do { asm volatile("s_waitcnt lgkmcnt(0)" ::: "memory"); \
                   __builtin_amdgcn_sched_barrier(0); } while (0)
#define VM6 do { asm volatile("s_waitcnt vmcnt(6)" ::: "memory"); \
                 __builtin_amdgcn_sched_barrier(0); } while (0)
#define MMQ(AF, BF, MB, NB)                                                   \
  do {                                                                        \
    __builtin_amdgcn_s_setprio(1);                                            \
    _Pragma("unroll") for (int mf = 0; mf < 4; ++mf)                          \
      _Pragma("unroll") for (int nf = 0; nf < 2; ++nf) {                      \
        acc[(MB) + mf][(NB) + nf] =                                           \
            mfma16(AF[mf][0], BF[nf][0], acc[(MB) + mf][(NB) + nf]);          \
        acc[(MB) + mf][(NB) + nf] =                                           \
            mfma16(AF[mf][1], BF[nf][1], acc[(MB) + mf][(NB) + nf]);          \
      }                                                                       \
    __builtin_amdgcn_s_setprio(0);                                            \
  } while (0)

template <int EPI>
__global__ __launch_bounds__(512, 2) void gemmT(
    const ushort* __restrict__ A, const ushort* __restrict__ Bt,
    const float* __restrict__ bias, const float* __restrict__ resid,
    float* __restrict__ outf, ushort* __restrict__ outh,
    int N, int K, int NT, int n_valid) {
  __shared__ ushort lA[2][256 * 64]; // 64KB
  __shared__ ushort lB[2][256 * 64]; // 64KB
  const int tid = threadIdx.x;
  const int lane = tid & 63, wave = tid >> 6;
  const int l15 = lane & 15, lg = lane >> 4;
  const int wr = wave >> 2, wc = wave & 3;

  // XCD-aware swizzle (all grids %8==0)
  const int nx = gridDim.x, ny = gridDim.y;
  const int nwg = nx * ny * gridDim.z;
  int flat = (blockIdx.z * ny + blockIdx.y) * nx + blockIdx.x;
  flat = (flat & 7) * (nwg >> 3) + (flat >> 3);
  const int bx = flat % nx;
  const int rem = flat / nx;
  const int by = rem % ny;
  const int bz = rem / ny;
  const int m0 = by * 256, n0 = bx * 256;
  const int k0 = bz * NT * 64;

  // staging
  const int rb8 = tid >> 3;
  const int swz = ((tid & 7) ^ (rb8 & 7)) * 8;
  const ushort* Ag = A + (size_t)m0 * K + k0 + swz;
  const ushort* Bg = Bt + (size_t)n0 * K + k0 + swz;
  const int rB = (rb8 & 31) + ((rb8 >> 5) << 6);
  const int rBw = (wave & 3) * 8 + (wave >> 2) * 64;

  auto stA = [&](int b, int u, int t) { // u 0: rows{0-63,128-191} 1: +64
#pragma unroll
    for (int j = 0; j < 2; ++j) {
      const int r = u * 64 + rb8 + j * 128;
      gload_lds16(Ag + (size_t)r * K + t * 64,
                  &lA[b][(u * 64 + wave * 8 + j * 128) * 64]);
    }
  };
  auto stB = [&](int b, int c, int t) { // c 0: B-first stripes 1: B-second
#pragma unroll
    for (int j = 0; j < 2; ++j) {
      const int r = rB + c * 32 + j * 128;
      gload_lds16(Bg + (size_t)r * K + t * 64,
                  &lB[b][(rBw + c * 32 + j * 128) * 64]);
    }
  };

  // fragment reads
  const int arow = wr * 128 + l15;
  const int brow = wc * 64 + l15;
  const int cp0 = ((0 + lg) ^ (l15 & 7)) * 8;
  const int cp1 = ((4 + lg) ^ (l15 & 7)) * 8;
  auto rdA = [&](int b, int half, short8 (&a)[4][2]) {
#pragma unroll
    for (int mf = 0; mf < 4; ++mf) {
      const ushort* p = &lA[b][(arow + half * 64 + mf * 16) * 64];
      a[mf][0] = *(const short8*)(p + cp0);
      a[mf][1] = *(const short8*)(p + cp1);
    }
  };
  auto rdB = [&](int b, int h, short8 (&bb)[2][2]) {
#pragma unroll
    for (int nf = 0; nf < 2; ++nf) {
      const ushort* p = &lB[b][(brow + h * 32 + nf * 16) * 64];
      bb[nf][0] = *(const short8*)(p + cp0);
      bb[nf][1] = *(const short8*)(p + cp1);
    }
  };

  f32x4 acc[8][4] = {};
  short8 aL[4][2], aH[4][2], b01[2][2], b23[2][2];

  // prologue: stage T0 (buf0), T1 (buf1); certify T0 (leave T1's 8 in flight)
  stA(0, 0, 0); stB(0, 0, 0); stA(0, 1, 0); stB(0, 1, 0);
  stA(1, 0, 1); stB(1, 0, 1); stA(1, 1, 1); stB(1, 1, 1);
  asm volatile("s_waitcnt vmcnt(8)" ::: "memory");
  BAR;
  rdA(0, 0, aL); rdB(0, 0, b01);

  const int NIT = NT >> 1; // NT even at all call sites
  for (int it = 0; it < NIT; ++it) {
    const int tn0 = 2 * it + 2, tn1 = 2 * it + 3;
    const bool more = (it + 1 < NIT);
    // ph1: Q1(T0)=aLxb01; rd b23(T0); stage T2.Alow
    rdB(0, 1, b23); if (more) stA(0, 0, tn0);
    BAR; LGKM0; MMQ(aL, b01, 0, 0); BAR;
    // ph2: Q2=aLxb23; rd aH(T0); stage T2.Bfst
    rdA(0, 1, aH); if (more) stB(0, 0, tn0);
    BAR; LGKM0; MMQ(aL, b23, 0, 2); BAR;
    // ph3: Q3=aHxb01; stage T2.Aup; vmcnt(6) checkpoint
    if (more) stA(0, 1, tn0);
    BAR; LGKM0; MMQ(aH, b01, 4, 0); VM6; BAR;
    // ph4: Q4=aHxb23; rd aL,b01(T1); stage T2.Bsnd
    rdA(1, 0, aL); rdB(1, 0, b01); if (more) stB(0, 1, tn0);
    BAR; LGKM0; MMQ(aH, b23, 4, 2); BAR;
    // ph5: Q1(T1); rd b23(T1); stage T3.Alow
    rdB(1, 1, b23); if (more) stA(1, 0, tn1);
    BAR; LGKM0; MMQ(aL, b01, 0, 0); BAR;
    // ph6: Q2(T1); rd aH(T1); stage T3.Bfst
    rdA(1, 1, aH); if (more) stB(1, 0, tn1);
    BAR; LGKM0; MMQ(aL, b23, 0, 2); BAR;
    // ph7: Q3(T1); stage T3.Aup; vmcnt(6) checkpoint
    if (more) stA(1, 1, tn1);
    BAR; LGKM0; MMQ(aH, b01, 4, 0); VM6; BAR;
    // ph8: Q4(T1); rd aL,b01(next T0); stage T3.Bsnd
    rdA(0, 0, aL); rdB(0, 0, b01); if (more) stB(1, 1, tn1);
    BAR; LGKM0; MMQ(aH, b23, 4, 2); BAR;
  }

  // epilogue
  float* outp = outf;
  if constexpr (EPI == 0) outp = outf + (size_t)bz * 4096 * 1152;
#pragma unroll
  for (int nf = 0; nf < 4; ++nf) {
    const int col = n0 + wc * 64 + nf * 16 + l15;
    if (col >= n_valid) continue;
    const float bv = (EPI != 0) ? bias[col] : 0.f;
#pragma unroll
    for (int mf = 0; mf < 8; ++mf) {
#pragma unroll
      for (int r = 0; r < 4; ++r) {
        const int row = m0 + wr * 128 + mf * 16 + lg * 4 + r;
        const size_t idx = (size_t)row * N + col;
        const float v = acc[mf][nf][r] + bv;
        if constexpr (EPI == 0) outp[idx] = v;
        else if constexpr (EPI == 1) outf[idx] = resid[idx] + v;
        else if constexpr (EPI == 2) outh[idx] = f2bf(gelu_tanh(v));
        else outh[idx] = f2bf(v);
      }
    }
  }
}

// ---------------- split-K reduce: out = hb + bias(col) + p0 + p1   (f32x4)
__global__ __launch_bounds__(256) void ksum_reduce(
    const float* __restrict__ hb, const float* __restrict__ bias,
    const float* __restrict__ p0, const float* __restrict__ p1,
    float* __restrict__ out) {
  const f32x4* hb4 = (const f32x4*)hb;
  const f32x4* b4 = (const f32x4*)bias;
  const f32x4* p04 = (const f32x4*)p0;
  const f32x4* p14 = (const f32x4*)p1;
  f32x4* o4 = (f32x4*)out;
  const int total = 4096 * 288; // 4096 x 1152 / 4
  for (int i = blockIdx.x * 256 + threadIdx.x; i < total; i += gridDim.x * 256)
    o4[i] = hb4[i] + b4[i % 288] + p04[i] + p14[i];
}

// ---------------- RoPE + pack q,k (vectorized): qkv bf16 (S,3456) ->
// q_pad,k_pad bf16 (H,S,96); thread = one 8-wide d-chunk (12 per (s,h))
__global__ __launch_bounds__(256) void rope_pack(
    const ushort* __restrict__ qkv,
    const float* __restrict__ cosp, const float* __restrict__ sinp,
    ushort* __restrict__ qp, ushort* __restrict__ kp) {
  const int t = blockIdx.x * 256 + threadIdx.x; // 4096*16*12 total
  const int c = t % 12;
  const int hs = t / 12;
  const int h = hs & 15;
  const int s = hs >> 4;
  const size_t dst = ((size_t)h * 4096 + s) * 96 + c * 8;
  if (c >= 9) {
    short8 z = {};
    *(short8*)(qp + dst) = z;
    *(short8*)(kp + dst) = z;
    return;
  }
  const size_t base = (size_t)s * 3456 + h * 72 + c * 8;
  const short8 qv = *(const short8*)(qkv + base);
  const short8 kv = *(const short8*)(qkv + base + 1152);
  const f32x4 cs = *(const f32x4*)(cosp + s * 36 + c * 4);
  const f32x4 sn = *(const f32x4*)(sinp + s * 36 + c * 4);
  short8 qo, ko;
#pragma unroll
  for (int j = 0; j < 4; ++j) {
    const float q0 = bf2f((ushort)qv[2 * j]), q1 = bf2f((ushort)qv[2 * j + 1]);
    const float k0 = bf2f((ushort)kv[2 * j]), k1 = bf2f((ushort)kv[2 * j + 1]);
    qo[2 * j] = (short)f2bf((q0 * cs[j] - q1 * sn[j]) * 0.1178511302f);
    qo[2 * j + 1] = (short)f2bf((q0 * sn[j] + q1 * cs[j]) * 0.1178511302f);
    ko[2 * j] = (short)f2bf(k0 * cs[j] - k1 * sn[j]);
    ko[2 * j + 1] = (short)f2bf(k0 * sn[j] + k1 * cs[j]);
  }
  *(short8*)(qp + dst) = qo;
  *(short8*)(kp + dst) = ko;
}

// ---------------- V pack + transpose: qkv bf16 -> vt bf16 (H,96,S), d>=72 zero
__global__ void v_pack(const ushort* __restrict__ qkv, ushort* __restrict__ vt) {
  __shared__ ushort lv[96][64];
  const int b = blockIdx.x;
  const int h = b >> 6;
  const int s0 = (b & 63) << 6;
  const int tid = threadIdx.x;
#pragma unroll
  for (int it = 0; it < 24; ++it) {
    int idx = tid + it * 256; // 96*64
    int d = idx % 96, sl = idx / 96;
    lv[d][sl] = (d < 72) ? qkv[(size_t)(s0 + sl) * 3456 + 2304 + h * 72 + d] : (ushort)0;
  }
  __syncthreads();
#pragma unroll
  for (int it = 0; it < 24; ++it) {
    int idx = tid + it * 256;
    int d = idx >> 6, sl = idx & 63;
    vt[((size_t)h * 96 + d) * 4096 + s0 + sl] = lv[d][sl];
  }
}

// ---------------- block-diagonal flash attention
// grid: 16 heads * 8 segs * 8 qtiles = 1024 blocks; 4 waves, 16 q-rows each
__global__ __launch_bounds__(256) void attn_kernel(
    const ushort* __restrict__ qp, const ushort* __restrict__ kp,
    const ushort* __restrict__ vt, ushort* __restrict__ attn_out) {
  __shared__ ushort lp[4][16 * 32];
  const int tid = threadIdx.x, lane = tid & 63, wave = tid >> 6;
  const int l15 = lane & 15, lg = lane >> 4;
  const int b = blockIdx.x;
  const int h = b >> 6;
  const int rem = b & 63;
  const int seg = rem >> 3, qt = rem & 7;
  const int q0 = seg * 512 + qt * 64 + wave * 16;

  short8 aq[3];
  const ushort* qrow = qp + ((size_t)h * 4096 + q0 + l15) * 96 + lg * 8;
  aq[0] = *(const short8*)(qrow);
  aq[1] = *(const short8*)(qrow + 32);
  aq[2] = *(const short8*)(qrow + 64);

  f32x4 oacc[5] = {};
  float mrow[4] = {-1e30f, -1e30f, -1e30f, -1e30f};
  float srow[4] = {0.f, 0.f, 0.f, 0.f};

  const ushort* kbase = kp + ((size_t)h * 4096 + seg * 512) * 96;
  const ushort* vbase = vt + (size_t)h * 96 * 4096 + seg * 512;
  ushort* lpw = lp[wave];

  for (int kc = 0; kc < 16; ++kc) {
    f32x4 sc[2] = {};
#pragma unroll
    for (int n = 0; n < 2; ++n) {
      const ushort* krow = kbase + (size_t)(kc * 32 + n * 16 + l15) * 96 + lg * 8;
#pragma unroll
      for (int c = 0; c < 3; ++c) {
        short8 kb = *(const short8*)(krow + c * 32);
        sc[n] = mfma16(aq[c], kb, sc[n]);
      }
    }
    float corr[4];
#pragma unroll
    for (int j = 0; j < 4; ++j) {
      float v = fmaxf(sc[0][j], sc[1][j]);
      v = fmaxf(v, __shfl_xor(v, 1));
      v = fmaxf(v, __shfl_xor(v, 2));
      v = fmaxf(v, __shfl_xor(v, 4));
      v = fmaxf(v, __shfl_xor(v, 8));
      float mn = fmaxf(mrow[j], v);
      corr[j] = __expf(mrow[j] - mn);
      mrow[j] = mn;
    }
    float p0[4], p1[4];
#pragma unroll
    for (int j = 0; j < 4; ++j) {
      p0[j] = __expf(sc[0][j] - mrow[j]);
      p1[j] = __expf(sc[1][j] - mrow[j]);
      float ps = p0[j] + p1[j];
      ps += __shfl_xor(ps, 1);
      ps += __shfl_xor(ps, 2);
      ps += __shfl_xor(ps, 4);
      ps += __shfl_xor(ps, 8);
      srow[j] = srow[j] * corr[j] + ps;
    }
#pragma unroll
    for (int n = 0; n < 5; ++n)
#pragma unroll
      for (int j = 0; j < 4; ++j)
        oacc[n][j] *= corr[j];
    // P (16x32) -> LDS transpose staging
#pragma unroll
    for (int j = 0; j < 4; ++j) {
      int row = lg * 4 + j;
      lpw[row * 32 + l15] = f2bf(p0[j]);
      lpw[row * 32 + 16 + l15] = f2bf(p1[j]);
    }
    __syncthreads();
    short8 pa = *(const short8*)&lpw[l15 * 32 + lg * 8];
    const ushort* vrow = vbase + kc * 32 + lg * 8;
#pragma unroll
    for (int n = 0; n < 5; ++n) {
      short8 vb = *(const short8*)(vrow + (size_t)(n * 16 + l15) * 4096);
      oacc[n] = mfma16(pa, vb, oacc[n]);
    }
    __syncthreads();
  }
#pragma unroll
  for (int j = 0; j < 4; ++j) {
    float inv = 1.f / srow[j];
    int row = q0 + lg * 4 + j;
#pragma unroll
    for (int n = 0; n < 5; ++n) {
      int col = n * 16 + l15;
      if (col < 72)
        attn_out[(size_t)row * 1152 + h * 72 + col] = f2bf(oacc[n][j] * inv);
    }
  }
}

// ---------------- launch
extern "C" void kernel_launch(void* const* d_in, const int* in_sizes, int n_in,
                              void* d_out, int out_size, void* d_ws, size_t ws_size,
                              hipStream_t stream) {
  (void)in_sizes; (void)n_in; (void)out_size;
  const float* hidden = (const float*)d_in[0];
  // d_in[1] = cu_seqlens: always arange(9)*512, handled structurally
  const float* ropec = (const float*)d_in[2];
  const float* ropes = (const float*)d_in[3];
  const float* n0s = (const float*)d_in[4];
  const float* n0b = (const float*)d_in[5];
  const float* wqkv = (const float*)d_in[6];
  const float* bqkv = (const float*)d_in[7];
  const float* wo = (const float*)d_in[8];
  const float* bo = (const float*)d_in[9];
  const float* n1s = (const float*)d_in[10];
  const float* n1b = (const float*)d_in[11];
  const float* wfc0 = (const float*)d_in[12];
  const float* bfc0 = (const float*)d_in[13];
  const float* wfc1 = (const float*)d_in[14];
  const float* bfc1 = (const float*)d_in[15];
  float* out = (float*)d_out;

  char* ws = (char*)d_ws;
  // workspace layout (bytes)
  ushort* x_bf   = (ushort*)(ws + 0);            //  9,437,184 (4096x1152)
  ushort* wqkv_t = (ushort*)(ws + 9437184);      //  8,257,536 (3584x1152)
  ushort* wo_t   = (ushort*)(ws + 17694720);     //  2,949,120 (1280x1152)
  ushort* fc0_t  = (ushort*)(ws + 20643840);     // 10,027,008 (4352x1152)
  ushort* fc1_t  = (ushort*)(ws + 30670848);     // 11,141,120 (1280x4352)
  ushort* qkv_bf = (ushort*)(ws + 41811968);     // 28,311,552 (4096x3456)
  ushort* mid    = (ushort*)(ws + 41811968);     // 35,651,584 (4096x4352) aliases qkv_bf (dead by then)
  ushort* q_pad  = (ushort*)(ws + 77463552);     // 12,582,912 (16x4096x96)
  ushort* k_pad  = (ushort*)(ws + 90046464);     // 12,582,912
  ushort* vt     = (ushort*)(ws + 102629376);    // 12,582,912 (16x96x4096)
  float*  pbuf   = (float*)(ws + 77463552);      // 37,748,736 (2x 4096x1152 f32) aliases q_pad..vt (dead after attn)
  ushort* attn   = (ushort*)(ws + 115212288);    //  9,437,184 (4096x1152)
  float*  hbuf   = (float*)(ws + 124649472);     // 18,874,368 (4096x1152 f32)
  ushort* yln    = (ushort*)(ws + 143523840);    //  9,437,184
  if (ws_size < 152961024) return;

  // 1. weight transposes (f32 KxN -> bf16 NPxKP, zero-padded)
  wconv_t<<<dim3(36, 112), 256, 0, stream>>>(wqkv, wqkv_t, 1152, 3456, 3584, 1152);
  wconv_t<<<dim3(36, 40), 256, 0, stream>>>(wo, wo_t, 1152, 1152, 1280, 1152);
  wconv_t<<<dim3(36, 136), 256, 0, stream>>>(wfc0, fc0_t, 1152, 4304, 4352, 1152);
  wconv_t<<<dim3(136, 40), 256, 0, stream>>>(wfc1, fc1_t, 4304, 1152, 1280, 4352);

  // 2. LN0
  ln_bf16<<<4096, 256, 0, stream>>>(hidden, n0s, n0b, x_bf);

  // 3. QKV GEMM -> bf16 (N padded 3584: grid 14x16 = 224, NT=18)
  gemmT<3><<<dim3(14, 16), 512, 0, stream>>>(x_bf, wqkv_t, bqkv, nullptr, nullptr, qkv_bf,
                                             3456, 1152, 18, 3456);
  // 4. RoPE pack q,k ; 5. V transpose
  rope_pack<<<3072, 256, 0, stream>>>(qkv_bf, ropec, ropes, q_pad, k_pad);
  v_pack<<<1024, 256, 0, stream>>>(qkv_bf, vt);

  // 6. attention
  attn_kernel<<<1024, 256, 0, stream>>>(q_pad, k_pad, vt, attn);

  // 7. WO GEMM + residual -> h (N padded 1280: grid 5x16 = 80, NT=18)
  gemmT<1><<<dim3(5, 16), 512, 0, stream>>>(attn, wo_t, bo, hidden, hbuf, nullptr,
                                            1152, 1152, 18, 1152);
  // 8. LN1
  ln_bf16<<<4096, 256, 0, stream>>>(hbuf, n1s, n1b, yln);

  // 9. FC0 GEMM + gelu -> mid (grid 17x16 = 272, NT=18)
  gemmT<2><<<dim3(17, 16), 512, 0, stream>>>(yln, fc0_t, bfc0, nullptr, nullptr, mid,
                                             4352, 1152, 18, 4304);
  // 10. FC1 GEMM split-K2 -> partials (grid 5x16x2 = 160, NT=34, Kwin=2176)
  gemmT<0><<<dim3(5, 16, 2), 512, 0, stream>>>(mid, fc1_t, nullptr, nullptr, pbuf, nullptr,
                                               1152, 4352, 34, 1152);
  // 11. reduce: out = hbuf + bias + p0 + p1
  ksum_reduce<<<2048, 256, 0, stream>>>(hbuf, bfc1, pbuf, pbuf + (size_t)4096 * 1152, out);
}

// Round 7
// 371.106 us; speedup vs baseline: 1.0813x; 1.0813x over previous
//
#include <hip/hip_runtime.h>

// MoonVitEncoderLayer on MI355X (gfx950).
// S=4096, D=1152, H=16, HD=72 (padded to 96), MLPD=4304 (padded to 4352).
// cu_seqlens is always arange(9)*512 -> block-diagonal attention, 8 segs of 512.
// R6: back to R2's proven 2-phase BK=32 GEMM (3-5 blocks/CU for latency hiding),
//     + column-major XCD-chunked block order (B-slice L2-resident per XCD),
//     + balanced XOR bank swizzle. Tiles: 256x128 (qkv,fc0), 128x128 (wo,fc1);
//     fc1 split-K2 + f32 reduce.

#define DEV __device__ __forceinline__

typedef __attribute__((ext_vector_type(8))) short short8;
typedef __attribute__((ext_vector_type(4))) float f32x4;

typedef const void __attribute__((address_space(1))) gvoid;
typedef void __attribute__((address_space(3))) lvoid;

DEV ushort f2bf(float f) {
  union { float f; unsigned u; } x; x.f = f;
  unsigned r = (x.u + 0x7FFFu + ((x.u >> 16) & 1u)) >> 16;
  return (ushort)r;
}

DEV float bf2f(ushort u) {
  union { unsigned u; float f; } x; x.u = (unsigned)u << 16;
  return x.f;
}

DEV void gload_lds16(const void* g, void* l) {
  __builtin_amdgcn_global_load_lds((gvoid*)g, (lvoid*)l, 16, 0, 0);
}

DEV f32x4 mfma16(short8 a, short8 b, f32x4 c) {
  return __builtin_amdgcn_mfma_f32_16x16x32_bf16(a, b, c, 0, 0, 0);
}

DEV float gelu_tanh(float x) {
  float x3 = x * x * x;
  return 0.5f * x * (1.f + tanhf(0.7978845608f * (x + 0.044715f * x3)));
}

// ---------------- weight convert + transpose: src f32 (K,N) -> dst bf16 (NP,KP), zero-padded
__global__ void wconv_t(const float* __restrict__ src, ushort* __restrict__ dst,
                        int K, int N, int NP, int KP) {
  __shared__ float tile[32][33];
  const int k0 = blockIdx.x * 32, n0 = blockIdx.y * 32;
  const int tx = threadIdx.x & 31, ty = threadIdx.x >> 5; // ty 0..7
#pragma unroll
  for (int i = 0; i < 4; ++i) {
    int r = ty + i * 8;
    float v = 0.f;
    if (k0 + r < K && n0 + tx < N) v = src[(size_t)(k0 + r) * N + n0 + tx];
    tile[tx][r] = v;
  }
  __syncthreads();
#pragma unroll
  for (int i = 0; i < 4; ++i) {
    int r = ty + i * 8;
    dst[(size_t)(n0 + r) * KP + k0 + tx] = f2bf(tile[r][tx]);
  }
}

// ---------------- LayerNorm row kernel: f32 (4096,1152) -> bf16
__global__ __launch_bounds__(256) void ln_bf16(const float* __restrict__ x,
                                               const float* __restrict__ sc,
                                               const float* __restrict__ bi,
                                               ushort* __restrict__ out) {
  const int row = blockIdx.x, tid = threadIdx.x;
  const float* xr = x + (size_t)row * 1152;
  const int n = (tid < 128) ? 5 : 4;
  float vals[5];
  float s = 0.f, s2 = 0.f;
#pragma unroll
  for (int i = 0; i < 5; ++i) {
    if (i < n) { float v = xr[tid + i * 256]; vals[i] = v; s += v; s2 += v * v; }
  }
#pragma unroll
  for (int off = 32; off; off >>= 1) { s += __shfl_xor(s, off); s2 += __shfl_xor(s2, off); }
  __shared__ float rs[4], rs2[4];
  if ((tid & 63) == 0) { rs[tid >> 6] = s; rs2[tid >> 6] = s2; }
  __syncthreads();
  s = rs[0] + rs[1] + rs[2] + rs[3];
  s2 = rs2[0] + rs2[1] + rs2[2] + rs2[3];
  const float mean = s * (1.f / 1152.f);
  const float var = s2 * (1.f / 1152.f) - mean * mean;
  const float rstd = rsqrtf(var + 1e-5f);
  ushort* orow = out + (size_t)row * 1152;
  for (int i = 0; i < n; ++i) {
    int c = tid + i * 256;
    orow[c] = f2bf((vals[i] - mean) * rstd * sc[c] + bi[c]);
  }
}

// ---------------- GEMM: A (M,K) bf16 rm, Bt (N,K) bf16 rm, C = A*B
// R2-proven 2-phase double-buffer, BK=32. BM x 128 tile.
// BM=256: 512 thr (8 waves 4Mx2N); BM=128: 256 thr (4 waves 2Mx2N);
// per-wave 64x64 (acc[4][4]) both. LDS 48KB / 32KB -> 3-5 blocks/CU.
// Block order: column-major flat (by fastest) chunked per XCD -> each XCD's
// B-slice (nx/8 cols x 0.3MB) is L2-resident; A streams via L3.
// Bank swizzle: global k-chunk pre-swizzled (c&3)^(row&3), read with
// cph = (lg ^ (l15&3))*8 -> balanced across bank quads.
// EPI 0: split-K partial (no bias)  1: resid+C+bias  2: bf16(gelu(C+bias))
// EPI 3: bf16(C+bias)
template <int EPI, int BM>
__global__ __launch_bounds__(BM == 256 ? 512 : 256, 2) void gemm2(
    const ushort* __restrict__ A, const ushort* __restrict__ Bt,
    const float* __restrict__ bias, const float* __restrict__ resid,
    float* __restrict__ outf, ushort* __restrict__ outh,
    int N, int Kstride, int NT, int n_valid) {
  constexpr int T = BM * 2;      // threads
  constexpr int NLA = 2;         // A gloads/thread (BM*4 chunks / T)
  constexpr int NLB = 512 / T;   // B gloads/thread
  __shared__ ushort lA[2][BM * 32];
  __shared__ ushort lB[2][128 * 32];
  const int tid = threadIdx.x;
  const int lane = tid & 63, wave = tid >> 6;
  const int l15 = lane & 15, lg = lane >> 4;

  // column-major flat + bijective XCD chunking (all grids %8 == 0)
  const int nx = gridDim.x, ny = gridDim.y;
  const int nwg = nx * ny * gridDim.z;
  const int hw = (blockIdx.z * ny + blockIdx.y) * nx + blockIdx.x;
  const int F = (hw & 7) * (nwg >> 3) + (hw >> 3); // xcd gets contiguous F range
  const int by = F % ny;
  const int C = F / ny;
  const int bx = C % nx;
  const int bz = C / nx;
  const int m0 = by * BM, n0 = bx * 128;
  const int k0 = bz * NT * 32;

  const int wm = (wave >> 1) * 64;
  const int wn = (wave & 1) * 64;

  // staging source addresses (pre-swizzled global k-chunk)
  const ushort* Asrc[NLA];
  const ushort* Bsrc[NLB];
#pragma unroll
  for (int i = 0; i < NLA; ++i) {
    const int c = i * T + tid;
    const int r = c >> 2, kc = (c & 3) ^ (r & 3);
    Asrc[i] = A + (size_t)(m0 + r) * Kstride + k0 + kc * 8;
  }
#pragma unroll
  for (int j = 0; j < NLB; ++j) {
    const int c = j * T + tid;
    const int r = c >> 2, kc = (c & 3) ^ (r & 3);
    Bsrc[j] = Bt + (size_t)(n0 + r) * Kstride + k0 + kc * 8;
  }

  auto stage = [&](int b, int t) {
#pragma unroll
    for (int i = 0; i < NLA; ++i)
      gload_lds16(Asrc[i] + t * 32, &lA[b][(i * T + wave * 64) * 8]);
#pragma unroll
    for (int j = 0; j < NLB; ++j)
      gload_lds16(Bsrc[j] + t * 32, &lB[b][(j * T + wave * 64) * 8]);
  };

  f32x4 acc[4][4] = {};
  const int cph = (lg ^ (l15 & 3)) * 8;

  stage(0, 0);
  __syncthreads();
  int cur = 0;
  for (int t = 0; t < NT; ++t) {
    if (t + 1 < NT) stage(cur ^ 1, t + 1); // in flight during ds_read + MFMA
    short8 af[4], bfr[4];
#pragma unroll
    for (int i = 0; i < 4; ++i)
      af[i] = *(const short8*)&lA[cur][(wm + i * 16 + l15) * 32 + cph];
#pragma unroll
    for (int j = 0; j < 4; ++j)
      bfr[j] = *(const short8*)&lB[cur][(wn + j * 16 + l15) * 32 + cph];
#pragma unroll
    for (int i = 0; i < 4; ++i)
#pragma unroll
      for (int j = 0; j < 4; ++j)
        acc[i][j] = mfma16(af[i], bfr[j], acc[i][j]);
    __syncthreads(); // drains vmcnt(0)+lgkmcnt(0): t+1 landed, buf[cur] free
    cur ^= 1;
  }

  // epilogue
  float* outp = outf;
  if constexpr (EPI == 0) outp = outf + (size_t)bz * 4096 * 1152;
  const int cb = n0 + wn + l15;
  const int rb = m0 + wm + lg * 4;
#pragma unroll
  for (int j = 0; j < 4; ++j) {
    const int col = cb + j * 16;
    const float bv = (EPI != 0 && col < n_valid) ? bias[col] : 0.f;
    const bool ok = (col < n_valid);
#pragma unroll
    for (int i = 0; i < 4; ++i) {
#pragma unroll
      for (int r = 0; r < 4; ++r) {
        const int row = rb + i * 16 + r;
        const size_t idx = (size_t)row * N + col;
        const float v = acc[i][j][r] + bv;
        if constexpr (EPI == 0) outp[idx] = v;
        else if constexpr (EPI == 1) { if (ok) outf[idx] = resid[idx] + v; }
        else if constexpr (EPI == 2) outh[idx] = f2bf(gelu_tanh(v));
        else outh[idx] = f2bf(v);
      }
    }
  }
}

// ---------------- split-K reduce: out = hb + bias(col) + p0 + p1   (f32x4)
__global__ __launch_bounds__(256) void ksum_reduce(
    const float* __restrict__ hb, const float* __restrict__ bias,
    const float* __restrict__ p0, const float* __restrict__ p1,
    float* __restrict__ out) {
  const f32x4* hb4 = (const f32x4*)hb;
  const f32x4* b4 = (const f32x4*)bias;
  const f32x4* p04 = (const f32x4*)p0;
  const f32x4* p14 = (const f32x4*)p1;
  f32x4* o4 = (f32x4*)out;
  const int total = 4096 * 288; // 4096 x 1152 / 4
  for (int i = blockIdx.x * 256 + threadIdx.x; i < total; i += gridDim.x * 256)
    o4[i] = hb4[i] + b4[i % 288] + p04[i] + p14[i];
}

// ---------------- RoPE + pack q,k (vectorized): qkv bf16 (S,3456) ->
// q_pad,k_pad bf16 (H,S,96); thread = one 8-wide d-chunk (12 per (s,h))
__global__ __launch_bounds__(256) void rope_pack(
    const ushort* __restrict__ qkv,
    const float* __restrict__ cosp, const float* __restrict__ sinp,
    ushort* __restrict__ qp, ushort* __restrict__ kp) {
  const int t = blockIdx.x * 256 + threadIdx.x; // 4096*16*12 total
  const int c = t % 12;
  const int hs = t / 12;
  const int h = hs & 15;
  const int s = hs >> 4;
  const size_t dst = ((size_t)h * 4096 + s) * 96 + c * 8;
  if (c >= 9) {
    short8 z = {};
    *(short8*)(qp + dst) = z;
    *(short8*)(kp + dst) = z;
    return;
  }
  const size_t base = (size_t)s * 3456 + h * 72 + c * 8;
  const short8 qv = *(const short8*)(qkv + base);
  const short8 kv = *(const short8*)(qkv + base + 1152);
  const f32x4 cs = *(const f32x4*)(cosp + s * 36 + c * 4);
  const f32x4 sn = *(const f32x4*)(sinp + s * 36 + c * 4);
  short8 qo, ko;
#pragma unroll
  for (int j = 0; j < 4; ++j) {
    const float q0 = bf2f((ushort)qv[2 * j]), q1 = bf2f((ushort)qv[2 * j + 1]);
    const float k0 = bf2f((ushort)kv[2 * j]), k1 = bf2f((ushort)kv[2 * j + 1]);
    qo[2 * j] = (short)f2bf((q0 * cs[j] - q1 * sn[j]) * 0.1178511302f);
    qo[2 * j + 1] = (short)f2bf((q0 * sn[j] + q1 * cs[j]) * 0.1178511302f);
    ko[2 * j] = (short)f2bf(k0 * cs[j] - k1 * sn[j]);
    ko[2 * j + 1] = (short)f2bf(k0 * sn[j] + k1 * cs[j]);
  }
  *(short8*)(qp + dst) = qo;
  *(short8*)(kp + dst) = ko;
}

// ---------------- V pack + transpose: qkv bf16 -> vt bf16 (H,96,S), d>=72 zero
__global__ void v_pack(const ushort* __restrict__ qkv, ushort* __restrict__ vt) {
  __shared__ ushort lv[96][64];
  const int b = blockIdx.x;
  const int h = b >> 6;
  const int s0 = (b & 63) << 6;
  const int tid = threadIdx.x;
#pragma unroll
  for (int it = 0; it < 24; ++it) {
    int idx = tid + it * 256; // 96*64
    int d = idx % 96, sl = idx / 96;
    lv[d][sl] = (d < 72) ? qkv[(size_t)(s0 + sl) * 3456 + 2304 + h * 72 + d] : (ushort)0;
  }
  __syncthreads();
#pragma unroll
  for (int it = 0; it < 24; ++it) {
    int idx = tid + it * 256;
    int d = idx >> 6, sl = idx & 63;
    vt[((size_t)h * 96 + d) * 4096 + s0 + sl] = lv[d][sl];
  }
}

// ---------------- block-diagonal flash attention
// grid: 16 heads * 8 segs * 8 qtiles = 1024 blocks; 4 waves, 16 q-rows each
__global__ __launch_bounds__(256) void attn_kernel(
    const ushort* __restrict__ qp, const ushort* __restrict__ kp,
    const ushort* __restrict__ vt, ushort* __restrict__ attn_out) {
  __shared__ ushort lp[4][16 * 32];
  const int tid = threadIdx.x, lane = tid & 63, wave = tid >> 6;
  const int l15 = lane & 15, lg = lane >> 4;
  const int b = blockIdx.x;
  const int h = b >> 6;
  const int rem = b & 63;
  const int seg = rem >> 3, qt = rem & 7;
  const int q0 = seg * 512 + qt * 64 + wave * 16;

  short8 aq[3];
  const ushort* qrow = qp + ((size_t)h * 4096 + q0 + l15) * 96 + lg * 8;
  aq[0] = *(const short8*)(qrow);
  aq[1] = *(const short8*)(qrow + 32);
  aq[2] = *(const short8*)(qrow + 64);

  f32x4 oacc[5] = {};
  float mrow[4] = {-1e30f, -1e30f, -1e30f, -1e30f};
  float srow[4] = {0.f, 0.f, 0.f, 0.f};

  const ushort* kbase = kp + ((size_t)h * 4096 + seg * 512) * 96;
  const ushort* vbase = vt + (size_t)h * 96 * 4096 + seg * 512;
  ushort* lpw = lp[wave];

  for (int kc = 0; kc < 16; ++kc) {
    f32x4 sc[2] = {};
#pragma unroll
    for (int n = 0; n < 2; ++n) {
      const ushort* krow = kbase + (size_t)(kc * 32 + n * 16 + l15) * 96 + lg * 8;
#pragma unroll
      for (int c = 0; c < 3; ++c) {
        short8 kb = *(const short8*)(krow + c * 32);
        sc[n] = mfma16(aq[c], kb, sc[n]);
      }
    }
    float corr[4];
#pragma unroll
    for (int j = 0; j < 4; ++j) {
      float v = fmaxf(sc[0][j], sc[1][j]);
      v = fmaxf(v, __shfl_xor(v, 1));
      v = fmaxf(v, __shfl_xor(v, 2));
      v = fmaxf(v, __shfl_xor(v, 4));
      v = fmaxf(v, __shfl_xor(v, 8));
      float mn = fmaxf(mrow[j], v);
      corr[j] = __expf(mrow[j] - mn);
      mrow[j] = mn;
    }
    float p0[4], p1[4];
#pragma unroll
    for (int j = 0; j < 4; ++j) {
      p0[j] = __expf(sc[0][j] - mrow[j]);
      p1[j] = __expf(sc[1][j] - mrow[j]);
      float ps = p0[j] + p1[j];
      ps += __shfl_xor(ps, 1);
      ps += __shfl_xor(ps, 2);
      ps += __shfl_xor(ps, 4);
      ps += __shfl_xor(ps, 8);
      srow[j] = srow[j] * corr[j] + ps;
    }
#pragma unroll
    for (int n = 0; n < 5; ++n)
#pragma unroll
      for (int j = 0; j < 4; ++j)
        oacc[n][j] *= corr[j];
    // P (16x32) -> LDS transpose staging
#pragma unroll
    for (int j = 0; j < 4; ++j) {
      int row = lg * 4 + j;
      lpw[row * 32 + l15] = f2bf(p0[j]);
      lpw[row * 32 + 16 + l15] = f2bf(p1[j]);
    }
    __syncthreads();
    short8 pa = *(const short8*)&lpw[l15 * 32 + lg * 8];
    const ushort* vrow = vbase + kc * 32 + lg * 8;
#pragma unroll
    for (int n = 0; n < 5; ++n) {
      short8 vb = *(const short8*)(vrow + (size_t)(n * 16 + l15) * 4096);
      oacc[n] = mfma16(pa, vb, oacc[n]);
    }
    __syncthreads();
  }
#pragma unroll
  for (int j = 0; j < 4; ++j) {
    float inv = 1.f / srow[j];
    int row = q0 + lg * 4 + j;
#pragma unroll
    for (int n = 0; n < 5; ++n) {
      int col = n * 16 + l15;
      if (col < 72)
        attn_out[(size_t)row * 1152 + h * 72 + col] = f2bf(oacc[n][j] * inv);
    }
  }
}

// ---------------- launch
extern "C" void kernel_launch(void* const* d_in, const int* in_sizes, int n_in,
                              void* d_out, int out_size, void* d_ws, size_t ws_size,
                              hipStream_t stream) {
  (void)in_sizes; (void)n_in; (void)out_size;
  const float* hidden = (const float*)d_in[0];
  // d_in[1] = cu_seqlens: always arange(9)*512, handled structurally
  const float* ropec = (const float*)d_in[2];
  const float* ropes = (const float*)d_in[3];
  const float* n0s = (const float*)d_in[4];
  const float* n0b = (const float*)d_in[5];
  const float* wqkv = (const float*)d_in[6];
  const float* bqkv = (const float*)d_in[7];
  const float* wo = (const float*)d_in[8];
  const float* bo = (const float*)d_in[9];
  const float* n1s = (const float*)d_in[10];
  const float* n1b = (const float*)d_in[11];
  const float* wfc0 = (const float*)d_in[12];
  const float* bfc0 = (const float*)d_in[13];
  const float* wfc1 = (const float*)d_in[14];
  const float* bfc1 = (const float*)d_in[15];
  float* out = (float*)d_out;

  char* ws = (char*)d_ws;
  // workspace layout (bytes)
  ushort* x_bf   = (ushort*)(ws + 0);            //  9,437,184 (4096x1152)
  ushort* wqkv_t = (ushort*)(ws + 9437184);      //  7,962,624 (3456x1152)
  ushort* wo_t   = (ushort*)(ws + 17399808);     //  2,654,208 (1152x1152)
  ushort* fc0_t  = (ushort*)(ws + 20054016);     // 10,027,008 (4352x1152)
  ushort* fc1_t  = (ushort*)(ws + 30081024);     // 10,027,008 (1152x4352)
  ushort* qkv_bf = (ushort*)(ws + 40108032);     // 28,311,552 (4096x3456)
  ushort* mid    = (ushort*)(ws + 40108032);     // 35,651,584 (4096x4352) aliases qkv_bf (dead by then)
  ushort* q_pad  = (ushort*)(ws + 75759616);     // 12,582,912 (16x4096x96)
  ushort* k_pad  = (ushort*)(ws + 88342528);     // 12,582,912
  ushort* vt     = (ushort*)(ws + 100925440);    // 12,582,912 (16x96x4096)
  float*  pbuf   = (float*)(ws + 75759616);      // 37,748,736 (2x 4096x1152 f32) aliases q_pad..vt (dead after attn)
  ushort* attn   = (ushort*)(ws + 113508352);    //  9,437,184 (4096x1152)
  float*  hbuf   = (float*)(ws + 122945536);     // 18,874,368 (4096x1152 f32)
  ushort* yln    = (ushort*)(ws + 141819904);    //  9,437,184
  if (ws_size < 151257088) return;

  // 1. weight transposes (f32 KxN -> bf16 NPxKP)
  wconv_t<<<dim3(36, 108), 256, 0, stream>>>(wqkv, wqkv_t, 1152, 3456, 3456, 1152);
  wconv_t<<<dim3(36, 36), 256, 0, stream>>>(wo, wo_t, 1152, 1152, 1152, 1152);
  wconv_t<<<dim3(36, 136), 256, 0, stream>>>(wfc0, fc0_t, 1152, 4304, 4352, 1152);
  wconv_t<<<dim3(136, 36), 256, 0, stream>>>(wfc1, fc1_t, 4304, 1152, 1152, 4352);

  // 2. LN0
  ln_bf16<<<4096, 256, 0, stream>>>(hidden, n0s, n0b, x_bf);

  // 3. QKV GEMM -> bf16 (256x128: grid 27x16 = 432, NT=36)
  gemm2<3, 256><<<dim3(27, 16), 512, 0, stream>>>(x_bf, wqkv_t, bqkv, nullptr, nullptr, qkv_bf,
                                                  3456, 1152, 36, 3456);
  // 4. RoPE pack q,k ; 5. V transpose
  rope_pack<<<3072, 256, 0, stream>>>(qkv_bf, ropec, ropes, q_pad, k_pad);
  v_pack<<<1024, 256, 0, stream>>>(qkv_bf, vt);

  // 6. attention
  attn_kernel<<<1024, 256, 0, stream>>>(q_pad, k_pad, vt, attn);

  // 7. WO GEMM + residual -> h (128x128: grid 9x32 = 288, NT=36)
  gemm2<1, 128><<<dim3(9, 32), 256, 0, stream>>>(attn, wo_t, bo, hidden, hbuf, nullptr,
                                                 1152, 1152, 36, 1152);
  // 8. LN1
  ln_bf16<<<4096, 256, 0, stream>>>(hbuf, n1s, n1b, yln);

  // 9. FC0 GEMM + gelu -> mid (256x128: grid 34x16 = 544, NT=36)
  gemm2<2, 256><<<dim3(34, 16), 512, 0, stream>>>(yln, fc0_t, bfc0, nullptr, nullptr, mid,
                                                  4352, 1152, 36, 4304);
  // 10. FC1 GEMM split-K2 -> partials (128x128: grid 9x32x2 = 576, NT=68)
  gemm2<0, 128><<<dim3(9, 32, 2), 256, 0, stream>>>(mid, fc1_t, nullptr, nullptr, pbuf, nullptr,
                                                    1152, 4352, 68, 1152);
  // 11. reduce: out = hbuf + bias + p0 + p1
  ksum_reduce<<<2048, 256, 0, stream>>>(hbuf, bfc1, pbuf, pbuf + (size_t)4096 * 1152, out);
}